// Round 11
// baseline (514.087 us; speedup 1.0000x reference)
//
#include <hip/hip_runtime.h>
#include <hip/hip_bf16.h>

// Problem constants
#define B_DIM   512
#define IN_DIM  4096
#define OUT_DIM 11008
#define PB      (B_DIM * OUT_DIM)   // one partial buffer (fp32 elems)

typedef __bf16 bf16x4 __attribute__((ext_vector_type(4)));
typedef __bf16 bf16x8 __attribute__((ext_vector_type(8)));
typedef float  floatx4 __attribute__((ext_vector_type(4)));

// ---------------------------------------------------------------------------
// Pass 1: x fp32 -> bf16
// ---------------------------------------------------------------------------
__global__ __launch_bounds__(256) void conv_x_kernel(
    const float* __restrict__ x, __bf16* __restrict__ xb) {
  int idx = blockIdx.x * blockDim.x + threadIdx.x;
  float4 v = ((const float4*)x)[idx];
  bf16x4 o;
  o[0] = (__bf16)v.x; o[1] = (__bf16)v.y; o[2] = (__bf16)v.z; o[3] = (__bf16)v.w;
  ((bf16x4*)xb)[idx] = o;
}

// ---------------------------------------------------------------------------
// Pass 2: fused QINS-decode + GEMM, v10.
// Diagnosis from v2/v3/v7/v9 (all 214-225 us, all pipes <=25%): per-tile
// wall scales with per-tile work while nothing saturates -> latency-stretch
// on the per-wave serial chain with <3 waves/SIMD to fill gaps. TLP was the
// never-moved axis. Fix:
//  - BM=128 x BN=64 x BK=32, split-K=2 -> 1376 blocks; LDS 24 KB +
//    launch_bounds(256,5) -> 5 blocks/CU -> 20 waves/CU (5/SIMD, 1.9x v9),
//    grid = 1.07 rounds.
//  - acc 4x2 (32 regs) keeps unified reg footprint ~95 <= 102 cap.
//  - v9's proven body verbatim otherwise: ONE barrier/tile; B raw loads at
//    body top (full-body cover to the barrier drain); decode 1-ahead ->
//    ds_write decoded bf16; floor-level XOR swizzle (0 conflicts, v9-
//    verified); fp32 partials + tiny reduce.
// ---------------------------------------------------------------------------
__device__ __forceinline__ void gl_lds16(const void* g, void* l) {
  __builtin_amdgcn_global_load_lds(
      (const __attribute__((address_space(1))) void*)g,
      (__attribute__((address_space(3))) void*)l, 16, 0, 0);
}

// w = sign * exp(lmin + (255 - s)/254 * (lmax - lmin)); sign-bit XOR
// (bit-exact to *(+-1): verified v5/v6/v7/v9 passed)
__device__ __forceinline__ float dec1f(int s, int g, float lmin, float slope) {
  float e = __expf(fmaf((float)(255 - s), slope, lmin));
  return __uint_as_float(__float_as_uint(e) ^ ((unsigned)g & 0x80000000u));
}

__device__ __forceinline__ bf16x8 dec8(int4 sl, int4 sh, int4 gl, int4 gh,
                                       float lmin, float slope) {
  bf16x8 w;
  w[0] = (__bf16)dec1f(sl.x, gl.x, lmin, slope);
  w[1] = (__bf16)dec1f(sl.y, gl.y, lmin, slope);
  w[2] = (__bf16)dec1f(sl.z, gl.z, lmin, slope);
  w[3] = (__bf16)dec1f(sl.w, gl.w, lmin, slope);
  w[4] = (__bf16)dec1f(sh.x, gh.x, lmin, slope);
  w[5] = (__bf16)dec1f(sh.y, gh.y, lmin, slope);
  w[6] = (__bf16)dec1f(sh.z, gh.z, lmin, slope);
  w[7] = (__bf16)dec1f(sh.w, gh.w, lmin, slope);
  return w;
}

__global__ __launch_bounds__(256, 5) void fused_qins_gemm_kernel(
    const __bf16* __restrict__ A,      // 512 x 4096 bf16 (pre-converted x)
    const int* __restrict__ stored,    // 11008 x 4096 int32 in [1,255]
    const int* __restrict__ sign,      // 11008 x 4096 int32 +-1
    const float* __restrict__ logmin, const float* __restrict__ logmax,
    float* __restrict__ part) {        // 2 x 512 x 11008 fp32 partials
  constexpr int K = IN_DIM, N = OUT_DIM;
  constexpr int BK = 32;
  constexpr int NT = 2048 / BK;        // 64 k-tiles per K-half

  __shared__ __align__(16) __bf16 sA[2][128 * BK];  // 2 x 8 KB
  __shared__ __align__(16) __bf16 sB[2][64 * BK];   // 2 x 4 KB  (24 KB total)

  const int tid  = threadIdx.x;
  const int lane = tid & 63;
  const int wave = tid >> 6;
  const int wm   = (wave >> 1) * 64;   // wave M offset (0/64)
  const int wn   = (wave & 1) * 32;    // wave N offset (0/32)
  const int m16  = lane & 15;
  const int q    = lane >> 4;          // 0..3

  // 1376 = 8 XCDs x 172. XCD swizzle: chunk c = wg&7 gets contiguous g-range
  // [172c, 172c+172) = 43 complete (bn,kh) panels; the 4 bm-blocks of each
  // panel are g-consecutive -> same XCD (stored/sign panel reuse in L2).
  const int wg  = blockIdx.x;                  // 0..1375
  const int g   = (wg & 7) * 172 + (wg >> 3);  // bijective
  const int bn0 = (g >> 3) * 64;               // 172 N-tiles
  const int kh  = (g >> 2) & 1;                // K-half
  const int bm0 = (g & 3) * 128;               // 4 M-tiles
  const int kbase = kh * 2048;

  const float lmin  = logmin[0];
  const float slope = (logmax[0] - lmin) * (1.0f / 254.0f);

  // ---- A staging: 2 gl_lds; chunk-XOR on the GLOBAL source (m173) ----
  // Rows are 64 B (4 chunks of 8 elems). Instr j, thread tid -> LDS
  // (row = j*64 + (tid>>2), slot = tid&3); slot holds chunk slot^(row&3);
  // (row&3) = (tid>>2)&3, invariant under +64.
  const int arow = tid >> 2;                  // 0..63
  const int achk = (tid & 3) ^ (arow & 3);
  const __bf16* gA0 = A + (size_t)(bm0 + arow) * K + kbase + achk * 8;
  const __bf16* gA1 = gA0 + (size_t)64 * K;

  // ---- B staging: 8 ints/thread (row tid>>2, chunk tid&3) ----
  const int rB = tid >> 2;                    // 0..63
  const int cB = tid & 3;
  const int* pS = stored + (size_t)(bn0 + rB) * K + kbase + cB * 8;
  const int* pG = sign   + (size_t)(bn0 + rB) * K + kbase + cB * 8;
  const int wOff = rB * BK + ((cB ^ (rB & 3)) * 8);

  // frag read slot: chunk q at rows with (row&3) = (m16&3)  [A and B alike]
  const int slotR = (q ^ (m16 & 3)) * 8;

  floatx4 acc[4][2] = {};

  // ---- Prologue: B(0)->sB[0]; A(0)->sA[0]; B(1)->regs; barrier ----
  int4 s0, s1, g0, g1;
  s0 = *(const int4*)(pS); s1 = *(const int4*)(pS + 4);
  g0 = *(const int4*)(pG); g1 = *(const int4*)(pG + 4);
  *(bf16x8*)&sB[0][wOff] = dec8(s0, s1, g0, g1, lmin, slope);
  gl_lds16(gA0, &sA[0][tid * 8]);
  gl_lds16(gA1, &sA[0][2048 + tid * 8]);
  s0 = *(const int4*)(pS + BK); s1 = *(const int4*)(pS + BK + 4);
  g0 = *(const int4*)(pG + BK); g1 = *(const int4*)(pG + BK + 4);
  __syncthreads();   // compiler drains vmcnt+lgkm: tile 0 resident, B(1) regs

  // Body t: decode B(t+1)->sB[c^1] (frees regs); issue raw B(t+2) loads and
  // gl_lds A(t+1) at the TOP (full-body cover to the end barrier's drain);
  // ds_read frags(t); 8 MFMA; one __syncthreads.
  for (int t = 0; t < NT; ++t) {
    const int c = t & 1;

    *(bf16x8*)&sB[c ^ 1][wOff] = dec8(s0, s1, g0, g1, lmin, slope);

    const int ktB = ((t + 2 < NT) ? (t + 2) : 0) * BK;
    s0 = *(const int4*)(pS + ktB); s1 = *(const int4*)(pS + ktB + 4);
    g0 = *(const int4*)(pG + ktB); g1 = *(const int4*)(pG + ktB + 4);

    const int ktA = ((t + 1 < NT) ? (t + 1) : 0) * BK;
    gl_lds16(gA0 + ktA, &sA[c ^ 1][tid * 8]);
    gl_lds16(gA1 + ktA, &sA[c ^ 1][2048 + tid * 8]);

    bf16x8 afr[4], bfr[2];
#pragma unroll
    for (int mi = 0; mi < 4; ++mi)
      afr[mi] = *(const bf16x8*)&sA[c][(wm + mi * 16 + m16) * BK + slotR];
#pragma unroll
    for (int ni = 0; ni < 2; ++ni)
      bfr[ni] = *(const bf16x8*)&sB[c][(wn + ni * 16 + m16) * BK + slotR];

#pragma unroll
    for (int mi = 0; mi < 4; ++mi)
#pragma unroll
      for (int ni = 0; ni < 2; ++ni)
        acc[mi][ni] = __builtin_amdgcn_mfma_f32_16x16x32_bf16(
            afr[mi], bfr[ni], acc[mi][ni], 0, 0, 0);

    __syncthreads();
  }

  // Epilogue: raw fp32 partial. C/D layout: col=lane&15, row=q*4+reg [m89]
  float* p = part + (size_t)kh * PB;
#pragma unroll
  for (int ni = 0; ni < 2; ++ni) {
    const int col = bn0 + wn + ni * 16 + m16;
#pragma unroll
    for (int mi = 0; mi < 4; ++mi) {
#pragma unroll
      for (int r = 0; r < 4; ++r) {
        const int row = bm0 + wm + mi * 16 + q * 4 + r;
        p[(size_t)row * N + col] = acc[mi][ni][r];
      }
    }
  }
}

// ---------------------------------------------------------------------------
// Pass 3: out = (p0 + p1 + bias) * scale    (float4, 11008 % 4 == 0)
// ---------------------------------------------------------------------------
__global__ __launch_bounds__(256) void reduce_kernel(
    const float* __restrict__ part, const float* __restrict__ scale,
    const float* __restrict__ bias, float* __restrict__ out) {
  const int i4  = blockIdx.x * blockDim.x + threadIdx.x;  // float4 index
  const int col = (i4 % (OUT_DIM / 4)) * 4;
  float4 a = ((const float4*)part)[i4];
  float4 b = ((const float4*)(part + PB))[i4];
  float4 sc = *(const float4*)(scale + col);
  float4 bb = *(const float4*)(bias + col);
  float4 o;
  o.x = (a.x + b.x + bb.x) * sc.x;
  o.y = (a.y + b.y + bb.y) * sc.y;
  o.z = (a.z + b.z + bb.z) * sc.z;
  o.w = (a.w + b.w + bb.w) * sc.w;
  ((float4*)out)[i4] = o;
}

// ---------------------------------------------------------------------------
extern "C" void kernel_launch(void* const* d_in, const int* in_sizes, int n_in,
                              void* d_out, int out_size, void* d_ws, size_t ws_size,
                              hipStream_t stream) {
  const float* x      = (const float*)d_in[0];
  const int*   stored = (const int*)d_in[1];
  const int*   sign   = (const int*)d_in[2];
  const float* logmin = (const float*)d_in[3];
  const float* logmax = (const float*)d_in[4];
  const float* scale  = (const float*)d_in[5];
  const float* bias   = (const float*)d_in[6];
  float* out = (float*)d_out;

  float*  wsP = (float*)d_ws;                     // 2 x 22.5 MB partials
  __bf16* wsX = (__bf16*)(wsP + 2 * (size_t)PB);  // 4 MB bf16 x

  conv_x_kernel<<<2048, 256, 0, stream>>>(x, wsX);
  // 172 bn x 2 kh x 4 bm = 1376 blocks (XCD-swizzled), 5 blocks/CU target
  fused_qins_gemm_kernel<<<1376, 256, 0, stream>>>(
      wsX, stored, sign, logmin, logmax, wsP);
  // 512*11008/4 float4s / 256 = 5504 blocks
  reduce_kernel<<<PB / 4 / 256, 256, 0, stream>>>(wsP, scale, bias, out);
}

// Round 12
// 498.048 us; speedup vs baseline: 1.0322x; 1.0322x over previous
//
#include <hip/hip_runtime.h>
#include <hip/hip_bf16.h>

// Problem constants
#define B_DIM   512
#define IN_DIM  4096
#define OUT_DIM 11008

typedef __bf16 bf16x4 __attribute__((ext_vector_type(4)));
typedef __bf16 bf16x8 __attribute__((ext_vector_type(8)));
typedef float  floatx4 __attribute__((ext_vector_type(4)));

// ---------------------------------------------------------------------------
// Pass 0: decode QINS -> bf16 W, grid-stride (2048 blocks, 8 elems/thr/iter).
// Round-0 version ran 119 us at 2.27 TB/s with 44032 tiny blocks; this is
// the launch-config fix (skill G11: cap ~2048 blocks + grid-stride).
// ---------------------------------------------------------------------------
__device__ __forceinline__ float dec1f(int s, int g, float lmin, float slope) {
  float e = __expf(fmaf((float)(255 - s), slope, lmin));
  return __uint_as_float(__float_as_uint(e) ^ ((unsigned)g & 0x80000000u));
}

__device__ __forceinline__ bf16x8 dec8(int4 sl, int4 sh, int4 gl, int4 gh,
                                       float lmin, float slope) {
  bf16x8 w;
  w[0] = (__bf16)dec1f(sl.x, gl.x, lmin, slope);
  w[1] = (__bf16)dec1f(sl.y, gl.y, lmin, slope);
  w[2] = (__bf16)dec1f(sl.z, gl.z, lmin, slope);
  w[3] = (__bf16)dec1f(sl.w, gl.w, lmin, slope);
  w[4] = (__bf16)dec1f(sh.x, gh.x, lmin, slope);
  w[5] = (__bf16)dec1f(sh.y, gh.y, lmin, slope);
  w[6] = (__bf16)dec1f(sh.z, gh.z, lmin, slope);
  w[7] = (__bf16)dec1f(sh.w, gh.w, lmin, slope);
  return w;
}

__global__ __launch_bounds__(256) void decode_w_kernel(
    const int* __restrict__ stored, const int* __restrict__ sign,
    const float* __restrict__ logmin, const float* __restrict__ logmax,
    __bf16* __restrict__ w) {
  const float lmin  = logmin[0];
  const float slope = (logmax[0] - lmin) * (1.0f / 254.0f);
  constexpr int nG = OUT_DIM * IN_DIM / 8;       // 5,636,096 groups of 8
  const int step = gridDim.x * blockDim.x;
  for (int i = blockIdx.x * blockDim.x + threadIdx.x; i < nG; i += step) {
    int4 s0 = ((const int4*)stored)[2 * i];
    int4 s1 = ((const int4*)stored)[2 * i + 1];
    int4 g0 = ((const int4*)sign)[2 * i];
    int4 g1 = ((const int4*)sign)[2 * i + 1];
    ((bf16x8*)w)[i] = dec8(s0, s1, g0, g1, lmin, slope);
  }
}

// ---------------------------------------------------------------------------
// Pass 1: x fp32 -> bf16
// ---------------------------------------------------------------------------
__global__ __launch_bounds__(256) void conv_x_kernel(
    const float* __restrict__ x, __bf16* __restrict__ xb) {
  int idx = blockIdx.x * blockDim.x + threadIdx.x;
  float4 v = ((const float4*)x)[idx];
  bf16x4 o;
  o[0] = (__bf16)v.x; o[1] = (__bf16)v.y; o[2] = (__bf16)v.z; o[3] = (__bf16)v.w;
  ((bf16x4*)xb)[idx] = o;
}

// ---------------------------------------------------------------------------
// Pass 2: pure bf16 GEMM, v7's proven shell with the decode machinery
// DELETED (decomposition from rounds 0-11: fused = pure-GEMM + ~115 us of
// per-tile decode-chain drain; round-0 pure GEMM implied ~100 us).
//  - BM=128 x BN=64 x BK=64, 688 blocks, LDS 48 KB -> 3 blocks/CU.
//  - ALL staging via global_load_lds (A 4 instrs, B 2 instrs per tile);
//    ONE __syncthreads per tile; loads issued at body top -> the barrier
//    drain waits on L2-warm loads issued a full body earlier.
//  - v7's XOR swizzle verbatim (measured 0 conflicts): 128-B LDS rows,
//    slot = chunk ^ (row&7), pre-swizzled on the GLOBAL source (m173).
//  - Epilogue fuses (acc + bias)*scale directly to out (no split-K).
// ---------------------------------------------------------------------------
__device__ __forceinline__ void gl_lds16(const void* g, void* l) {
  __builtin_amdgcn_global_load_lds(
      (const __attribute__((address_space(1))) void*)g,
      (__attribute__((address_space(3))) void*)l, 16, 0, 0);
}

__global__ __launch_bounds__(256, 3) void gemm_bt_kernel(
    const __bf16* __restrict__ A,      // 512 x 4096 bf16 (pre-converted x)
    const __bf16* __restrict__ Bw,     // 11008 x 4096 bf16 (decoded W)
    const float* __restrict__ scale, const float* __restrict__ bias,
    float* __restrict__ out) {
  constexpr int K = IN_DIM, N = OUT_DIM;
  constexpr int BK = 64;
  constexpr int NT = K / BK;           // 64 k-tiles

  __shared__ __align__(16) __bf16 sA[2][128 * BK];  // 2 x 16 KB
  __shared__ __align__(16) __bf16 sB[2][64 * BK];   // 2 x 8 KB  (48 KB)

  const int tid  = threadIdx.x;
  const int lane = tid & 63;
  const int wave = tid >> 6;
  const int wm   = (wave >> 1) * 64;   // wave M offset (0/64)
  const int wn   = (wave & 1) * 32;    // wave N offset (0/32)
  const int m16  = lane & 15;
  const int q    = lane >> 4;          // 0..3

  // XCD swizzle: 688 = 8 x 86 (bijective); the 4 bm-blocks of a bn panel
  // are g-consecutive -> same XCD (W-panel reuse in that XCD's L2).
  const int wg  = blockIdx.x;                 // 0..687
  const int g   = (wg & 7) * 86 + (wg >> 3);  // bijective
  const int bm0 = (g & 3) * 128;              // 4 M-tiles
  const int bn0 = (g >> 2) * 64;              // 172 N-tiles

  // ---- A staging: 4 gl_lds; 128-B rows; chunk-XOR on the GLOBAL source ----
  // Instr j, thread tid -> LDS (row = j*32 + (tid>>3), slot = tid&7);
  // slot holds global chunk slot ^ (row&7); (row&7) invariant across j.
  const int arow = tid >> 3;                  // 0..31
  const int achk = (tid & 7) ^ (arow & 7);
  const __bf16* gA = A + (size_t)(bm0 + arow) * K + achk * 8;

  // ---- B staging: 2 gl_lds; same algebra on the decoded-W workspace ----
  const __bf16* gB = Bw + (size_t)(bn0 + arow) * K + achk * 8;

  // frag read slots: chunk(kk) = 4*kk + q at rows with (row&7) = (m16&7)
  const int slotk0 = ((4 * 0 + q) ^ (m16 & 7)) * 8;
  const int slotk1 = ((4 * 1 + q) ^ (m16 & 7)) * 8;

  floatx4 acc[4][2] = {};

  // Prologue: stage tile 0 -> buf 0; barrier drains (compiler-inserted).
#pragma unroll
  for (int j = 0; j < 4; ++j)
    gl_lds16(gA + (size_t)j * 32 * K, &sA[0][j * 2048 + tid * 8]);
#pragma unroll
  for (int j = 0; j < 2; ++j)
    gl_lds16(gB + (size_t)j * 32 * K, &sB[0][j * 2048 + tid * 8]);
  __syncthreads();

  // Body t: stage t+1 -> buf c^1 at the TOP (one-body gap to the barrier
  // drain; L2-warm W/A); ds_read frags(t); 16 MFMA; one __syncthreads.
  for (int t = 0; t < NT; ++t) {
    const int c = t & 1;
    const int ktn = ((t + 1 < NT) ? (t + 1) : 0) * BK;  // clamp: dead reload
#pragma unroll
    for (int j = 0; j < 4; ++j)
      gl_lds16(gA + (size_t)j * 32 * K + ktn, &sA[c ^ 1][j * 2048 + tid * 8]);
#pragma unroll
    for (int j = 0; j < 2; ++j)
      gl_lds16(gB + (size_t)j * 32 * K + ktn, &sB[c ^ 1][j * 2048 + tid * 8]);

    bf16x8 afr[4][2], bfr[2][2];
#pragma unroll
    for (int mi = 0; mi < 4; ++mi) {
      const int rbase = (wm + mi * 16 + m16) * BK;
      afr[mi][0] = *(const bf16x8*)&sA[c][rbase + slotk0];
      afr[mi][1] = *(const bf16x8*)&sA[c][rbase + slotk1];
    }
#pragma unroll
    for (int ni = 0; ni < 2; ++ni) {
      const int rbase = (wn + ni * 16 + m16) * BK;
      bfr[ni][0] = *(const bf16x8*)&sB[c][rbase + slotk0];
      bfr[ni][1] = *(const bf16x8*)&sB[c][rbase + slotk1];
    }

#pragma unroll
    for (int kk = 0; kk < 2; ++kk)
#pragma unroll
      for (int mi = 0; mi < 4; ++mi)
#pragma unroll
        for (int ni = 0; ni < 2; ++ni)
          acc[mi][ni] = __builtin_amdgcn_mfma_f32_16x16x32_bf16(
              afr[mi][kk], bfr[ni][kk], acc[mi][ni], 0, 0, 0);

    __syncthreads();
  }

  // Epilogue. C/D layout: col = lane&15, row = q*4 + reg  [m89]
#pragma unroll
  for (int ni = 0; ni < 2; ++ni) {
    const int col = bn0 + wn + ni * 16 + m16;
    const float sc = scale[col];
    const float bb = bias[col] * sc;
#pragma unroll
    for (int mi = 0; mi < 4; ++mi) {
#pragma unroll
      for (int r = 0; r < 4; ++r) {
        const int row = bm0 + wm + mi * 16 + q * 4 + r;
        out[row * N + col] = acc[mi][ni][r] * sc + bb;
      }
    }
  }
}

// ---------------------------------------------------------------------------
extern "C" void kernel_launch(void* const* d_in, const int* in_sizes, int n_in,
                              void* d_out, int out_size, void* d_ws, size_t ws_size,
                              hipStream_t stream) {
  const float* x      = (const float*)d_in[0];
  const int*   stored = (const int*)d_in[1];
  const int*   sign   = (const int*)d_in[2];
  const float* logmin = (const float*)d_in[3];
  const float* logmax = (const float*)d_in[4];
  const float* scale  = (const float*)d_in[5];
  const float* bias   = (const float*)d_in[6];
  float* out = (float*)d_out;

  __bf16* wsW = (__bf16*)d_ws;                       // 11008*4096 bf16 = 90 MB
  __bf16* wsX = wsW + (size_t)OUT_DIM * IN_DIM;      // 512*4096 bf16 = 4 MB

  // decode W: grid-stride, 2048 blocks x 256 thr, 8 elems/thread/iter
  decode_w_kernel<<<2048, 256, 0, stream>>>(stored, sign, logmin, logmax, wsW);
  // convert x: 2048 blocks
  conv_x_kernel<<<2048, 256, 0, stream>>>(x, wsX);
  // GEMM: 172 bn x 4 bm = 688 blocks (XCD-swizzled), 3 blocks/CU
  gemm_bt_kernel<<<688, 256, 0, stream>>>(wsX, wsW, scale, bias, out);
}